// Round 14
// baseline (404.459 us; speedup 1.0000x reference)
//
#include <hip/hip_runtime.h>

// StyleGAN2 modulated transposed conv block, MI355X bf16-MFMA implementation.
// R14: conv identical to R13 except __launch_bounds__(512,6) -> 3 blocks/CU
//      (LDS 3x48=144KB <= 160, VGPR 64). Single-variable occupancy A/B.

typedef unsigned short u16;
typedef unsigned int u32;
typedef __bf16 bf16x8 __attribute__((ext_vector_type(8)));
typedef u16 u16x8 __attribute__((ext_vector_type(8)));
typedef float f32x4 __attribute__((ext_vector_type(4)));

#define CIN 512
#define COUT 256
#define XP 33   // padded xs spatial (32 + 1)
#define YP 68   // padded y spatial (64 + 2*2)
#define RS (XP*512)   // xs row stride in u16 = 16896

#define XS_BYTES  (16u*33*33*512*2)        // 17,842,176
#define YP_BYTES  (16u*68*68*256*2)        // 37,879,808
#define YB_BYTES  (16u*32*32*256*2)        //  8,388,608 (cls3b compact partial)
#define WBT_BYTES (9u*256*512*2)           //  2,359,296
#define WSQ_BYTES (512u*256*4)             //    524,288
#define STY_BYTES (16u*512*4)              //     32,768
#define DEM_BYTES (16u*256*4)              //     16,384

__device__ __forceinline__ u16 f2bf(float f) {
    u32 u = __float_as_uint(f);
    u32 r = (u + 0x7fffu + ((u >> 16) & 1u)) >> 16;
    return (u16)r;
}

__device__ __forceinline__ void gload16(const void* g, void* l) {
    __builtin_amdgcn_global_load_lds(
        (const __attribute__((address_space(1))) u32*)g,
        (__attribute__((address_space(3))) u32*)l, 16, 0, 0);
}

// ---------------- fuseA: style (64 blocks) + wsq (512 blocks) -----------------------
__global__ __launch_bounds__(256)
void fuseA_kernel(const float* __restrict__ s, const float* __restrict__ mod_w,
                  const float* __restrict__ mod_b, const float* __restrict__ weight,
                  float* __restrict__ style, float* __restrict__ wsq) {
    int bid = blockIdx.x, t = threadIdx.x;
    if (bid < 64) {
        int b = bid >> 2, q = bid & 3;
        __shared__ float ss[512];
        for (int i = t; i < 512; i += 256) ss[i] = s[b*512 + i];
        __syncthreads();
        int ci = q*128 + (t >> 1);
        int kh = (t & 1) * 256;
        const float* row = mod_w + (size_t)ci * 512 + kh;
        const float* sh = ss + kh;
        float acc = 0.f;
        for (int k = 0; k < 256; k += 4) {
            float4 m = *reinterpret_cast<const float4*>(row + k);
            acc += m.x*sh[k] + m.y*sh[k+1] + m.z*sh[k+2] + m.w*sh[k+3];
        }
        acc += __shfl_xor(acc, 1);
        if (!(t & 1)) style[b*512 + ci] = acc * 0.04419417382415922f + mod_b[ci];
    } else {
        int idx = (bid - 64) * 256 + t;   // 512*256
        const float* p = weight + (size_t)idx * 9;
        float a = 0.f;
        #pragma unroll
        for (int i = 0; i < 9; ++i) { float v = p[i]; a += v * v; }
        wsq[idx] = a;
    }
}

// ---------------- fuseB: demod (64 blocks) + wbt (2304 blocks) ----------------------
__global__ __launch_bounds__(256)
void fuseB_kernel(const float* __restrict__ style, const float* __restrict__ wsq,
                  const float* __restrict__ weight, float* __restrict__ demod,
                  u16* __restrict__ wbT) {
    int bid = blockIdx.x, t = threadIdx.x;
    if (bid < 64) {
        int b = bid >> 2, q = bid & 3;
        __shared__ float st2[512];
        for (int i = t; i < 512; i += 256) { float v = style[b*512 + i]; st2[i] = v * v; }
        __syncthreads();
        int co = q*64 + (t >> 2);
        int kq = (t & 3) * 128;
        float acc = 0.f;
        for (int ci = kq; ci < kq + 128; ++ci) acc += st2[ci] * wsq[ci*256 + co];
        acc += __shfl_xor(acc, 1);
        acc += __shfl_xor(acc, 2);
        if (!(t & 3)) demod[b*256 + co] = rsqrtf(acc * (1.0f/4608.0f) + 1e-8f);
    } else {
        int id = bid - 64;               // 0..2303
        int p = id >> 8, co = id & 255;
        u16* dst = wbT + ((size_t)p*256 + co)*512;
        const float* srcb = weight + co*9 + p;
        dst[t]       = f2bf(srcb[(size_t)t * 2304]);
        dst[t + 256] = f2bf(srcb[(size_t)(t + 256) * 2304]);
    }
}

// ---------------- norm: xs[b][h][w][ci] = x*rsqrt(mean_ci x^2 + eps)*style/sqrt4608 -
__global__ __launch_bounds__(256)
void norm_kernel(const float* __restrict__ x, const float* __restrict__ style,
                 u16* __restrict__ xs) {
    int h = blockIdx.x, b = blockIdx.y;
    int t = threadIdx.x;
    u16* xrow = xs + ((size_t)b*XP + h)*XP*512;
    if (h == 32) {                       // zero entire pad row (33*512 u16)
        u16x8 z = {0,0,0,0,0,0,0,0};
        for (int i = t; i < 2112; i += 256)
            reinterpret_cast<u16x8*>(xrow)[i] = z;
        return;
    }
    __shared__ float red[8][32];
    __shared__ float sscale[32];
    __shared__ float sstyle[512];
    __shared__ u16 tile[32*512];
    for (int i = t; i < 512; i += 256)
        sstyle[i] = style[b*512 + i] * 0.014731391274719739f;  // 1/sqrt(4608)
    int w = t & 31, cg = t >> 5;
    const float* xb = x + ((size_t)b*512*32 + h)*32;   // + ci*1024 + w

    float vv[64];
    float a = 0.f;
    #pragma unroll
    for (int i = 0; i < 64; ++i) {
        float v = xb[(size_t)(8*i + cg)*1024 + w];
        vv[i] = v;
        a += v * v;
    }
    red[cg][w] = a;
    __syncthreads();
    if (t < 32) {
        float s2 = 0.f;
        #pragma unroll
        for (int g = 0; g < 8; ++g) s2 += red[g][t];
        sscale[t] = rsqrtf(s2 * (1.0f/512.0f) + 1e-8f);
    }
    __syncthreads();
    float sc = sscale[w];
    #pragma unroll
    for (int i = 0; i < 64; ++i) {
        int ci = 8*i + cg;
        float v = vv[i] * sc * sstyle[ci];
        tile[w*512 + ((i ^ (w & 7)) * 8 + cg)] = f2bf(v);
    }
    if (t < 64) {
        u16x8 z = {0,0,0,0,0,0,0,0};
        reinterpret_cast<u16x8*>(xrow + 32*512)[t] = z;
    }
    __syncthreads();
    int wv = t >> 6, gi = t & 63;
    #pragma unroll
    for (int rr = 0; rr < 32; rr += 4) {
        int w2 = rr + wv;
        u16x8 v = *reinterpret_cast<const u16x8*>(&tile[w2*512 + ((gi ^ (w2 & 7)) * 8)]);
        *reinterpret_cast<u16x8*>(&xrow[w2*512 + gi*8]) = v;
    }
}

// ---------------- conv: 128Mx256N, BK=32, 8 waves, 3 blocks/CU ----------------------
// groups g5: 0=cls3a(taps p0,p2 -> ypad+bias) 1=cls3b(taps p6,p8 -> partial)
//            2=cls2 3=cls1 (S=32) 4=cls0 (S=16). 640 blocks, heavy first.
__global__ __launch_bounds__(512, 6)
void conv_mfma_kernel(const u16* __restrict__ xs, const u16* __restrict__ wbT,
                      const float* __restrict__ demod, const float* __restrict__ bias,
                      u16* __restrict__ ypad, u16* __restrict__ ypadB) {
    // per buf (12288 u16 = 24KB): A[128][32] @0, B[256][32] @4096
    __shared__ __align__(16) u16 sm[2*12288];

    const int zz = blockIdx.x;       // 0..639
    const int g5 = zz >> 7;          // 0:cls3a 1:cls3b 2:cls2 3:cls1 4:cls0
    const int sub = zz & 127;
    const int b = sub >> 3, mt = sub & 7;

    int py, px, aof0, aof1, bof0, bof1, S;
    bool toB = false, wbias = true;
    if (g5 == 0)      { py=1; px=1; aof0=RS+512; bof0=0;        aof1=RS; bof1=2*131072; S=32; }
    else if (g5 == 1) { py=1; px=1; aof0=512;    bof0=6*131072; aof1=0;  bof1=8*131072; S=32;
                        toB=true; wbias=false; }
    else if (g5 == 2) { py=1; px=0; aof0=RS;     bof0=1*131072; aof1=0;  bof1=7*131072; S=32; }
    else if (g5 == 3) { py=0; px=1; aof0=512;    bof0=3*131072; aof1=0;  bof1=5*131072; S=32; }
    else              { py=0; px=0; aof0=0;      bof0=4*131072; aof1=0;  bof1=4*131072; S=16; }

    const int t = threadIdx.x;       // 0..511
    const int lane = t & 63, w = t >> 6;
    const int wm0 = (w >> 2) * 64;   // M half: 0/64 (2 M-waves)
    const int wn0 = (w & 3) * 64;    // N quarter: 0/64/128/192 (4 N-waves)
    const int r = lane & 15, q = lane >> 4;
    const int qs = (q ^ ((r >> 1) & 3)) * 8;    // swizzled read granule (u16)
    const int a0 = mt * 4;           // 4 a-rows per block (BM=128)

    const int m0 = t >> 2;                           // staging row 0..127
    const int c8 = (((t & 3) ^ ((t >> 3) & 3))) * 8; // pre-swizzled source granule

    const u16* aB = xs + (size_t)b*XP*RS + ((a0 + (m0 >> 5))*XP + (m0 & 31))*512 + c8;
    const u16* bB = wbT + m0*512 + c8;

    f32x4 acc[4][4];
    #pragma unroll
    for (int i = 0; i < 4; ++i)
        #pragma unroll
        for (int j = 0; j < 4; ++j) { f32x4 z = {0.f,0.f,0.f,0.f}; acc[i][j] = z; }

    auto stage = [&](int s, int buf) {
        int aof = (s >> 4) ? aof1 : aof0;
        int bof = (s >> 4) ? bof1 : bof0;
        int k0 = (s & 15) << 5;
        u16* la = &sm[buf * 12288 + t * 8];
        gload16(aB + aof + k0,             la);            // A rows 0..127
        gload16(bB + bof + k0,             la + 4096);     // B rows 0..127
        gload16(bB + bof + k0 + 128*512,   la + 8192);     // B rows 128..255
    };

    stage(0, 0);

    for (int s = 0; s < S; ++s) {
        const int buf = s & 1;
        if (s + 1 < S) {
            stage(s + 1, buf ^ 1);
            asm volatile("s_waitcnt vmcnt(3)" ::: "memory");   // stage(s) landed
        } else {
            asm volatile("s_waitcnt vmcnt(0)" ::: "memory");
        }
        __builtin_amdgcn_s_barrier();

        const u16* smc = &sm[buf * 12288];
        bf16x8 af[4], bfr[4];
        #pragma unroll
        for (int mi = 0; mi < 4; ++mi)
            af[mi] = *reinterpret_cast<const bf16x8*>(&smc[(wm0 + mi*16 + r)*32 + qs]);
        #pragma unroll
        for (int ni = 0; ni < 4; ++ni)
            bfr[ni] = *reinterpret_cast<const bf16x8*>(&smc[4096 + (wn0 + ni*16 + r)*32 + qs]);

        // compiler-scheduled lgkm interleave (no forced drain)
        __builtin_amdgcn_s_setprio(1);
        #pragma unroll
        for (int mi = 0; mi < 4; ++mi)
            #pragma unroll
            for (int ni = 0; ni < 4; ++ni)
                acc[mi][ni] = __builtin_amdgcn_mfma_f32_16x16x32_bf16(
                    af[mi], bfr[ni], acc[mi][ni], 0, 0, 0);
        __builtin_amdgcn_s_setprio(0);
        __builtin_amdgcn_s_barrier();    // all waves done reading buf
    }

    // epilogue: val = acc*demod[b,co] (+ bias[co]); cls3b -> compact partial
    float dmv[4], bsv[4];
    #pragma unroll
    for (int ni = 0; ni < 4; ++ni) {
        int co = wn0 + ni*16 + r;
        dmv[ni] = demod[b*256 + co];
        bsv[ni] = wbias ? bias[co] : 0.f;
    }
    #pragma unroll
    for (int mi = 0; mi < 4; ++mi) {
        #pragma unroll
        for (int rg = 0; rg < 4; ++rg) {
            int m = wm0 + mi*16 + q*4 + rg;     // 0..127
            int a = a0 + (m >> 5), bc = m & 31;
            size_t rowbase;
            if (!toB) {
                int oy = 2*a + py + 2, ox = 2*bc + px + 2;
                rowbase = (((size_t)b*YP + oy)*YP + ox)*256;
            } else {
                rowbase = (((size_t)b*32 + a)*32 + bc)*256;
            }
            u16* dst = toB ? ypadB : ypad;
            #pragma unroll
            for (int ni = 0; ni < 4; ++ni) {
                int co = wn0 + ni*16 + r;
                float v = acc[mi][ni][rg] * dmv[ni] + bsv[ni];
                dst[rowbase + co] = f2bf(v);
            }
        }
    }
}

// ---------------- addp: ypad[odd-odd] += ypadB (coalesced RMW) ----------------------
__global__ __launch_bounds__(256)
void addp_kernel(u16* __restrict__ ypad, const u16* __restrict__ ypadB) {
    const int a = blockIdx.x;    // 0..31
    const int b = blockIdx.y;    // 0..15
    const int t = threadIdx.x;
    const u16* src = ypadB + ((size_t)(b*32 + a))*32*256;
    u16* dst = ypad + (((size_t)b*YP + 2*a + 3)*YP + 3)*256;
    #pragma unroll
    for (int i = 0; i < 4; ++i) {
        int f = i*2048 + t*8;
        int bc = f >> 8, co = f & 255;
        u16x8 pv = *reinterpret_cast<const u16x8*>(src + f);
        u16* dp = dst + bc*512 + co;
        u16x8 dv = *reinterpret_cast<const u16x8*>(dp);
        u16x8 ov;
        #pragma unroll
        for (int k = 0; k < 8; ++k) {
            float fv = __uint_as_float(((u32)pv[k]) << 16)
                     + __uint_as_float(((u32)dv[k]) << 16);
            ov[k] = f2bf(fv);
        }
        *reinterpret_cast<u16x8*>(dp) = ov;
    }
}

// ---------------- blur: separable 5x5 binomial + lrelu*sqrt2, 4 rows/block ----------
__global__ __launch_bounds__(256)
void blur_kernel(const u16* __restrict__ ypad, float* __restrict__ out) {
    const int cg  = blockIdx.x;   // 0..3 (64-channel chunk)
    const int oyq = blockIdx.y;   // 0..15 (4 oy rows each)
    const int b   = blockIdx.z;
    const int t = threadIdx.x;
    __shared__ float vlds[4][68][65];   // [oy][cx][ch]

    const int cp  = t & 31;       // channel pair
    const int cxi = t >> 5;       // 0..7
    const int oy0 = oyq * 4;
    const u16* base = ypad + ((size_t)b*YP + oy0)*YP*256 + cg*64 + cp*2;

    #pragma unroll
    for (int j = 0; j < 9; ++j) {
        int cx = j*8 + cxi;
        if (cx < 68) {
            bool cxok = (cx >= 2 && cx <= 65);
            float r0[8], r1[8];
            #pragma unroll
            for (int rr = 0; rr < 8; ++rr) {
                int iy = oy0 + rr;
                bool ok = cxok && (iy >= 2) && (iy <= 65);
                u32 u = ok ? *reinterpret_cast<const u32*>(base + ((size_t)rr*YP + cx)*256) : 0u;
                r0[rr] = __uint_as_float(u << 16);
                r1[rr] = __uint_as_float(u & 0xffff0000u);
            }
            #pragma unroll
            for (int o = 0; o < 4; ++o) {
                float a0 = 0.0625f*(r0[o]+r0[o+4]) + 0.25f*(r0[o+1]+r0[o+3]) + 0.375f*r0[o+2];
                float a1 = 0.0625f*(r1[o]+r1[o+4]) + 0.25f*(r1[o+1]+r1[o+3]) + 0.375f*r1[o+2];
                vlds[o][cx][cp*2]     = a0;
                vlds[o][cx][cp*2 + 1] = a1;
            }
        }
    }
    __syncthreads();

    const int oxl = t & 63;
    const int cq  = t >> 6;       // 0..3
    #pragma unroll
    for (int o = 0; o < 4; ++o) {
        float* ob = out + (((size_t)b*256 + cg*64)*64 + (oy0 + o))*64;
        #pragma unroll
        for (int i = 0; i < 16; ++i) {
            int c = cq*16 + i;
            float v = 0.0625f*(vlds[o][oxl][c] + vlds[o][oxl+4][c])
                    + 0.25f*(vlds[o][oxl+1][c] + vlds[o][oxl+3][c])
                    + 0.375f*vlds[o][oxl+2][c];
            v = (v >= 0.f ? v : 0.2f*v) * 1.4142135623730951f;
            ob[(size_t)c*4096 + oxl] = v;
        }
    }
}

extern "C" void kernel_launch(void* const* d_in, const int* in_sizes, int n_in,
                              void* d_out, int out_size, void* d_ws, size_t ws_size,
                              hipStream_t stream) {
    const float* x      = (const float*)d_in[0];
    const float* s      = (const float*)d_in[1];
    const float* weight = (const float*)d_in[2];
    const float* bias   = (const float*)d_in[3];
    const float* mod_w  = (const float*)d_in[4];
    const float* mod_b  = (const float*)d_in[5];
    float* out = (float*)d_out;

    char* ws = (char*)d_ws;
    size_t off = 0;
    u16*   xs    = (u16*)(ws + off); off += XS_BYTES;
    u16*   ypad  = (u16*)(ws + off); off += YP_BYTES;
    u16*   ypadB = (u16*)(ws + off); off += YB_BYTES;
    u16*   wbT   = (u16*)(ws + off); off += WBT_BYTES;
    float* wsq   = (float*)(ws + off); off += WSQ_BYTES;
    float* style = (float*)(ws + off); off += STY_BYTES;
    float* demod = (float*)(ws + off); off += DEM_BYTES;
    if (ws_size < off) return;  // workspace too small -> visible correctness failure

    fuseA_kernel<<<576, 256, 0, stream>>>(s, mod_w, mod_b, weight, style, wsq);
    fuseB_kernel<<<2368, 256, 0, stream>>>(style, wsq, weight, demod, wbT);
    norm_kernel<<<dim3(33, 16), 256, 0, stream>>>(x, style, xs);
    conv_mfma_kernel<<<640, 512, 0, stream>>>(xs, wbT, demod, bias, ypad, ypadB);
    addp_kernel<<<dim3(32, 16), 256, 0, stream>>>(ypad, ypadB);
    blur_kernel<<<dim3(4, 16, 16), 256, 0, stream>>>(ypad, out);
}

// Round 15
// 111.267 us; speedup vs baseline: 3.6350x; 3.6350x over previous
//
#include <hip/hip_runtime.h>

// StyleGAN2 modulated transposed conv block, MI355X bf16-MFMA implementation.
// R15: conv = exact R13 revert (128Mx256N, BK=32, 8 waves, launch_bounds(512,4),
//      2x24KB LDS, counted vmcnt(3)) — R14's (512,6) caused a spill cliff
//      (VGPR 40, FETCH 541MB). fuseB wbt path = R9's coalesced LDS transpose.

typedef unsigned short u16;
typedef unsigned int u32;
typedef __bf16 bf16x8 __attribute__((ext_vector_type(8)));
typedef u16 u16x8 __attribute__((ext_vector_type(8)));
typedef float f32x4 __attribute__((ext_vector_type(4)));

#define CIN 512
#define COUT 256
#define XP 33   // padded xs spatial (32 + 1)
#define YP 68   // padded y spatial (64 + 2*2)
#define RS (XP*512)   // xs row stride in u16 = 16896

#define XS_BYTES  (16u*33*33*512*2)        // 17,842,176
#define YP_BYTES  (16u*68*68*256*2)        // 37,879,808
#define YB_BYTES  (16u*32*32*256*2)        //  8,388,608 (cls3b compact partial)
#define WBT_BYTES (9u*256*512*2)           //  2,359,296
#define WSQ_BYTES (512u*256*4)             //    524,288
#define STY_BYTES (16u*512*4)              //     32,768
#define DEM_BYTES (16u*256*4)              //     16,384

__device__ __forceinline__ u16 f2bf(float f) {
    u32 u = __float_as_uint(f);
    u32 r = (u + 0x7fffu + ((u >> 16) & 1u)) >> 16;
    return (u16)r;
}

__device__ __forceinline__ void gload16(const void* g, void* l) {
    __builtin_amdgcn_global_load_lds(
        (const __attribute__((address_space(1))) u32*)g,
        (__attribute__((address_space(3))) u32*)l, 16, 0, 0);
}

// ---------------- fuseA: style (64 blocks) + wsq (512 blocks) -----------------------
__global__ __launch_bounds__(256)
void fuseA_kernel(const float* __restrict__ s, const float* __restrict__ mod_w,
                  const float* __restrict__ mod_b, const float* __restrict__ weight,
                  float* __restrict__ style, float* __restrict__ wsq) {
    int bid = blockIdx.x, t = threadIdx.x;
    if (bid < 64) {
        int b = bid >> 2, q = bid & 3;
        __shared__ float ss[512];
        for (int i = t; i < 512; i += 256) ss[i] = s[b*512 + i];
        __syncthreads();
        int ci = q*128 + (t >> 1);
        int kh = (t & 1) * 256;
        const float* row = mod_w + (size_t)ci * 512 + kh;
        const float* sh = ss + kh;
        float acc = 0.f;
        for (int k = 0; k < 256; k += 4) {
            float4 m = *reinterpret_cast<const float4*>(row + k);
            acc += m.x*sh[k] + m.y*sh[k+1] + m.z*sh[k+2] + m.w*sh[k+3];
        }
        acc += __shfl_xor(acc, 1);
        if (!(t & 1)) style[b*512 + ci] = acc * 0.04419417382415922f + mod_b[ci];
    } else {
        int idx = (bid - 64) * 256 + t;   // 512*256
        const float* p = weight + (size_t)idx * 9;
        float a = 0.f;
        #pragma unroll
        for (int i = 0; i < 9; ++i) { float v = p[i]; a += v * v; }
        wsq[idx] = a;
    }
}

// ---------------- fuseB: demod (64 blocks) + wbt LDS-transpose (64 blocks) ----------
__global__ __launch_bounds__(256)
void fuseB_kernel(const float* __restrict__ style, const float* __restrict__ wsq,
                  const float* __restrict__ weight, float* __restrict__ demod,
                  u16* __restrict__ wbT) {
    int bid = blockIdx.x, t = threadIdx.x;
    if (bid < 64) {
        int b = bid >> 2, q = bid & 3;
        __shared__ float st2[512];
        for (int i = t; i < 512; i += 256) { float v = style[b*512 + i]; st2[i] = v * v; }
        __syncthreads();
        int co = q*64 + (t >> 2);
        int kq = (t & 3) * 128;
        float acc = 0.f;
        for (int ci = kq; ci < kq + 128; ++ci) acc += st2[ci] * wsq[ci*256 + co];
        acc += __shfl_xor(acc, 1);
        acc += __shfl_xor(acc, 2);
        if (!(t & 3)) demod[b*256 + co] = rsqrtf(acc * (1.0f/4608.0f) + 1e-8f);
    } else {
        // transpose 8 ci-rows: wbT[p][co][ci0+cc] = bf16(weight[ci0+cc][co][p])
        int ci0 = (bid - 64) * 8;
        __shared__ u16 lw[2304][8];
        const float* wbase = weight + (size_t)ci0 * 2304;
        #pragma unroll
        for (int cc = 0; cc < 8; ++cc) {
            #pragma unroll
            for (int k = 0; k < 9; ++k) {
                int f = t + 256*k;
                lw[f][cc] = f2bf(wbase[(size_t)cc*2304 + f]);
            }
        }
        __syncthreads();
        #pragma unroll
        for (int k = 0; k < 9; ++k) {
            int f = t + 256*k;
            int p = f % 9, co = f / 9;
            u16x8 v = *reinterpret_cast<const u16x8*>(&lw[f][0]);
            *reinterpret_cast<u16x8*>(wbT + ((size_t)(p*256 + co))*512 + ci0) = v;
        }
    }
}

// ---------------- norm: xs[b][h][w][ci] = x*rsqrt(mean_ci x^2 + eps)*style/sqrt4608 -
__global__ __launch_bounds__(256)
void norm_kernel(const float* __restrict__ x, const float* __restrict__ style,
                 u16* __restrict__ xs) {
    int h = blockIdx.x, b = blockIdx.y;
    int t = threadIdx.x;
    u16* xrow = xs + ((size_t)b*XP + h)*XP*512;
    if (h == 32) {                       // zero entire pad row (33*512 u16)
        u16x8 z = {0,0,0,0,0,0,0,0};
        for (int i = t; i < 2112; i += 256)
            reinterpret_cast<u16x8*>(xrow)[i] = z;
        return;
    }
    __shared__ float red[8][32];
    __shared__ float sscale[32];
    __shared__ float sstyle[512];
    __shared__ u16 tile[32*512];
    for (int i = t; i < 512; i += 256)
        sstyle[i] = style[b*512 + i] * 0.014731391274719739f;  // 1/sqrt(4608)
    int w = t & 31, cg = t >> 5;
    const float* xb = x + ((size_t)b*512*32 + h)*32;   // + ci*1024 + w

    float vv[64];
    float a = 0.f;
    #pragma unroll
    for (int i = 0; i < 64; ++i) {
        float v = xb[(size_t)(8*i + cg)*1024 + w];
        vv[i] = v;
        a += v * v;
    }
    red[cg][w] = a;
    __syncthreads();
    if (t < 32) {
        float s2 = 0.f;
        #pragma unroll
        for (int g = 0; g < 8; ++g) s2 += red[g][t];
        sscale[t] = rsqrtf(s2 * (1.0f/512.0f) + 1e-8f);
    }
    __syncthreads();
    float sc = sscale[w];
    #pragma unroll
    for (int i = 0; i < 64; ++i) {
        int ci = 8*i + cg;
        float v = vv[i] * sc * sstyle[ci];
        tile[w*512 + ((i ^ (w & 7)) * 8 + cg)] = f2bf(v);
    }
    if (t < 64) {
        u16x8 z = {0,0,0,0,0,0,0,0};
        reinterpret_cast<u16x8*>(xrow + 32*512)[t] = z;
    }
    __syncthreads();
    int wv = t >> 6, gi = t & 63;
    #pragma unroll
    for (int rr = 0; rr < 32; rr += 4) {
        int w2 = rr + wv;
        u16x8 v = *reinterpret_cast<const u16x8*>(&tile[w2*512 + ((gi ^ (w2 & 7)) * 8)]);
        *reinterpret_cast<u16x8*>(&xrow[w2*512 + gi*8]) = v;
    }
}

// ---------------- conv: 128Mx256N, BK=32, 8 waves (R13 proven) ----------------------
// groups g5: 0=cls3a(taps p0,p2 -> ypad+bias) 1=cls3b(taps p6,p8 -> partial)
//            2=cls2 3=cls1 (S=32) 4=cls0 (S=16). 640 blocks, heavy first.
__global__ __launch_bounds__(512, 4)
void conv_mfma_kernel(const u16* __restrict__ xs, const u16* __restrict__ wbT,
                      const float* __restrict__ demod, const float* __restrict__ bias,
                      u16* __restrict__ ypad, u16* __restrict__ ypadB) {
    // per buf (12288 u16 = 24KB): A[128][32] @0, B[256][32] @4096
    __shared__ __align__(16) u16 sm[2*12288];

    const int zz = blockIdx.x;       // 0..639
    const int g5 = zz >> 7;          // 0:cls3a 1:cls3b 2:cls2 3:cls1 4:cls0
    const int sub = zz & 127;
    const int b = sub >> 3, mt = sub & 7;

    int py, px, aof0, aof1, bof0, bof1, S;
    bool toB = false, wbias = true;
    if (g5 == 0)      { py=1; px=1; aof0=RS+512; bof0=0;        aof1=RS; bof1=2*131072; S=32; }
    else if (g5 == 1) { py=1; px=1; aof0=512;    bof0=6*131072; aof1=0;  bof1=8*131072; S=32;
                        toB=true; wbias=false; }
    else if (g5 == 2) { py=1; px=0; aof0=RS;     bof0=1*131072; aof1=0;  bof1=7*131072; S=32; }
    else if (g5 == 3) { py=0; px=1; aof0=512;    bof0=3*131072; aof1=0;  bof1=5*131072; S=32; }
    else              { py=0; px=0; aof0=0;      bof0=4*131072; aof1=0;  bof1=4*131072; S=16; }

    const int t = threadIdx.x;       // 0..511
    const int lane = t & 63, w = t >> 6;
    const int wm0 = (w >> 2) * 64;   // M half: 0/64 (2 M-waves)
    const int wn0 = (w & 3) * 64;    // N quarter: 0/64/128/192 (4 N-waves)
    const int r = lane & 15, q = lane >> 4;
    const int qs = (q ^ ((r >> 1) & 3)) * 8;    // swizzled read granule (u16)
    const int a0 = mt * 4;           // 4 a-rows per block (BM=128)

    const int m0 = t >> 2;                           // staging row 0..127
    const int c8 = (((t & 3) ^ ((t >> 3) & 3))) * 8; // pre-swizzled source granule

    const u16* aB = xs + (size_t)b*XP*RS + ((a0 + (m0 >> 5))*XP + (m0 & 31))*512 + c8;
    const u16* bB = wbT + m0*512 + c8;

    f32x4 acc[4][4];
    #pragma unroll
    for (int i = 0; i < 4; ++i)
        #pragma unroll
        for (int j = 0; j < 4; ++j) { f32x4 z = {0.f,0.f,0.f,0.f}; acc[i][j] = z; }

    auto stage = [&](int s, int buf) {
        int aof = (s >> 4) ? aof1 : aof0;
        int bof = (s >> 4) ? bof1 : bof0;
        int k0 = (s & 15) << 5;
        u16* la = &sm[buf * 12288 + t * 8];
        gload16(aB + aof + k0,             la);            // A rows 0..127
        gload16(bB + bof + k0,             la + 4096);     // B rows 0..127
        gload16(bB + bof + k0 + 128*512,   la + 8192);     // B rows 128..255
    };

    stage(0, 0);

    for (int s = 0; s < S; ++s) {
        const int buf = s & 1;
        if (s + 1 < S) {
            stage(s + 1, buf ^ 1);
            asm volatile("s_waitcnt vmcnt(3)" ::: "memory");   // stage(s) landed
        } else {
            asm volatile("s_waitcnt vmcnt(0)" ::: "memory");
        }
        __builtin_amdgcn_s_barrier();

        const u16* smc = &sm[buf * 12288];
        bf16x8 af[4], bfr[4];
        #pragma unroll
        for (int mi = 0; mi < 4; ++mi)
            af[mi] = *reinterpret_cast<const bf16x8*>(&smc[(wm0 + mi*16 + r)*32 + qs]);
        #pragma unroll
        for (int ni = 0; ni < 4; ++ni)
            bfr[ni] = *reinterpret_cast<const bf16x8*>(&smc[4096 + (wn0 + ni*16 + r)*32 + qs]);

        // compiler-scheduled lgkm interleave (no forced drain)
        __builtin_amdgcn_s_setprio(1);
        #pragma unroll
        for (int mi = 0; mi < 4; ++mi)
            #pragma unroll
            for (int ni = 0; ni < 4; ++ni)
                acc[mi][ni] = __builtin_amdgcn_mfma_f32_16x16x32_bf16(
                    af[mi], bfr[ni], acc[mi][ni], 0, 0, 0);
        __builtin_amdgcn_s_setprio(0);
        __builtin_amdgcn_s_barrier();    // all waves done reading buf
    }

    // epilogue: val = acc*demod[b,co] (+ bias[co]); cls3b -> compact partial
    float dmv[4], bsv[4];
    #pragma unroll
    for (int ni = 0; ni < 4; ++ni) {
        int co = wn0 + ni*16 + r;
        dmv[ni] = demod[b*256 + co];
        bsv[ni] = wbias ? bias[co] : 0.f;
    }
    #pragma unroll
    for (int mi = 0; mi < 4; ++mi) {
        #pragma unroll
        for (int rg = 0; rg < 4; ++rg) {
            int m = wm0 + mi*16 + q*4 + rg;     // 0..127
            int a = a0 + (m >> 5), bc = m & 31;
            size_t rowbase;
            if (!toB) {
                int oy = 2*a + py + 2, ox = 2*bc + px + 2;
                rowbase = (((size_t)b*YP + oy)*YP + ox)*256;
            } else {
                rowbase = (((size_t)b*32 + a)*32 + bc)*256;
            }
            u16* dst = toB ? ypadB : ypad;
            #pragma unroll
            for (int ni = 0; ni < 4; ++ni) {
                int co = wn0 + ni*16 + r;
                float v = acc[mi][ni][rg] * dmv[ni] + bsv[ni];
                dst[rowbase + co] = f2bf(v);
            }
        }
    }
}

// ---------------- addp: ypad[odd-odd] += ypadB (coalesced RMW) ----------------------
__global__ __launch_bounds__(256)
void addp_kernel(u16* __restrict__ ypad, const u16* __restrict__ ypadB) {
    const int a = blockIdx.x;    // 0..31
    const int b = blockIdx.y;    // 0..15
    const int t = threadIdx.x;
    const u16* src = ypadB + ((size_t)(b*32 + a))*32*256;
    u16* dst = ypad + (((size_t)b*YP + 2*a + 3)*YP + 3)*256;
    #pragma unroll
    for (int i = 0; i < 4; ++i) {
        int f = i*2048 + t*8;
        int bc = f >> 8, co = f & 255;
        u16x8 pv = *reinterpret_cast<const u16x8*>(src + f);
        u16* dp = dst + bc*512 + co;
        u16x8 dv = *reinterpret_cast<const u16x8*>(dp);
        u16x8 ov;
        #pragma unroll
        for (int k = 0; k < 8; ++k) {
            float fv = __uint_as_float(((u32)pv[k]) << 16)
                     + __uint_as_float(((u32)dv[k]) << 16);
            ov[k] = f2bf(fv);
        }
        *reinterpret_cast<u16x8*>(dp) = ov;
    }
}

// ---------------- blur: separable 5x5 binomial + lrelu*sqrt2, 4 rows/block ----------
__global__ __launch_bounds__(256)
void blur_kernel(const u16* __restrict__ ypad, float* __restrict__ out) {
    const int cg  = blockIdx.x;   // 0..3 (64-channel chunk)
    const int oyq = blockIdx.y;   // 0..15 (4 oy rows each)
    const int b   = blockIdx.z;
    const int t = threadIdx.x;
    __shared__ float vlds[4][68][65];   // [oy][cx][ch]

    const int cp  = t & 31;       // channel pair
    const int cxi = t >> 5;       // 0..7
    const int oy0 = oyq * 4;
    const u16* base = ypad + ((size_t)b*YP + oy0)*YP*256 + cg*64 + cp*2;

    #pragma unroll
    for (int j = 0; j < 9; ++j) {
        int cx = j*8 + cxi;
        if (cx < 68) {
            bool cxok = (cx >= 2 && cx <= 65);
            float r0[8], r1[8];
            #pragma unroll
            for (int rr = 0; rr < 8; ++rr) {
                int iy = oy0 + rr;
                bool ok = cxok && (iy >= 2) && (iy <= 65);
                u32 u = ok ? *reinterpret_cast<const u32*>(base + ((size_t)rr*YP + cx)*256) : 0u;
                r0[rr] = __uint_as_float(u << 16);
                r1[rr] = __uint_as_float(u & 0xffff0000u);
            }
            #pragma unroll
            for (int o = 0; o < 4; ++o) {
                float a0 = 0.0625f*(r0[o]+r0[o+4]) + 0.25f*(r0[o+1]+r0[o+3]) + 0.375f*r0[o+2];
                float a1 = 0.0625f*(r1[o]+r1[o+4]) + 0.25f*(r1[o+1]+r1[o+3]) + 0.375f*r1[o+2];
                vlds[o][cx][cp*2]     = a0;
                vlds[o][cx][cp*2 + 1] = a1;
            }
        }
    }
    __syncthreads();

    const int oxl = t & 63;
    const int cq  = t >> 6;       // 0..3
    #pragma unroll
    for (int o = 0; o < 4; ++o) {
        float* ob = out + (((size_t)b*256 + cg*64)*64 + (oy0 + o))*64;
        #pragma unroll
        for (int i = 0; i < 16; ++i) {
            int c = cq*16 + i;
            float v = 0.0625f*(vlds[o][oxl][c] + vlds[o][oxl+4][c])
                    + 0.25f*(vlds[o][oxl+1][c] + vlds[o][oxl+3][c])
                    + 0.375f*vlds[o][oxl+2][c];
            v = (v >= 0.f ? v : 0.2f*v) * 1.4142135623730951f;
            ob[(size_t)c*4096 + oxl] = v;
        }
    }
}

extern "C" void kernel_launch(void* const* d_in, const int* in_sizes, int n_in,
                              void* d_out, int out_size, void* d_ws, size_t ws_size,
                              hipStream_t stream) {
    const float* x      = (const float*)d_in[0];
    const float* s      = (const float*)d_in[1];
    const float* weight = (const float*)d_in[2];
    const float* bias   = (const float*)d_in[3];
    const float* mod_w  = (const float*)d_in[4];
    const float* mod_b  = (const float*)d_in[5];
    float* out = (float*)d_out;

    char* ws = (char*)d_ws;
    size_t off = 0;
    u16*   xs    = (u16*)(ws + off); off += XS_BYTES;
    u16*   ypad  = (u16*)(ws + off); off += YP_BYTES;
    u16*   ypadB = (u16*)(ws + off); off += YB_BYTES;
    u16*   wbT   = (u16*)(ws + off); off += WBT_BYTES;
    float* wsq   = (float*)(ws + off); off += WSQ_BYTES;
    float* style = (float*)(ws + off); off += STY_BYTES;
    float* demod = (float*)(ws + off); off += DEM_BYTES;
    if (ws_size < off) return;  // workspace too small -> visible correctness failure

    fuseA_kernel<<<576, 256, 0, stream>>>(s, mod_w, mod_b, weight, style, wsq);
    fuseB_kernel<<<128, 256, 0, stream>>>(style, wsq, weight, demod, wbT);
    norm_kernel<<<dim3(33, 16), 256, 0, stream>>>(x, style, xs);
    conv_mfma_kernel<<<640, 512, 0, stream>>>(xs, wbT, demod, bias, ypad, ypadB);
    addp_kernel<<<dim3(32, 16), 256, 0, stream>>>(ypad, ypadB);
    blur_kernel<<<dim3(4, 16, 16), 256, 0, stream>>>(ypad, out);
}

// Round 16
// 110.698 us; speedup vs baseline: 3.6537x; 1.0051x over previous
//
#include <hip/hip_runtime.h>

// StyleGAN2 modulated transposed conv block, MI355X bf16-MFMA implementation.
// R16: conv = R13 + 3-buffer rotation (72KB LDS, still 2 blocks/CU) with ONE
//      barrier/step + vmcnt(3) (R8-proven schedule, ported to 8 waves), and
//      cls0-first dispatch (dynamic tail balancing). Rest unchanged from R15.

typedef unsigned short u16;
typedef unsigned int u32;
typedef __bf16 bf16x8 __attribute__((ext_vector_type(8)));
typedef u16 u16x8 __attribute__((ext_vector_type(8)));
typedef float f32x4 __attribute__((ext_vector_type(4)));

#define CIN 512
#define COUT 256
#define XP 33   // padded xs spatial (32 + 1)
#define YP 68   // padded y spatial (64 + 2*2)
#define RS (XP*512)   // xs row stride in u16 = 16896

#define XS_BYTES  (16u*33*33*512*2)        // 17,842,176
#define YP_BYTES  (16u*68*68*256*2)        // 37,879,808
#define YB_BYTES  (16u*32*32*256*2)        //  8,388,608 (cls3b compact partial)
#define WBT_BYTES (9u*256*512*2)           //  2,359,296
#define WSQ_BYTES (512u*256*4)             //    524,288
#define STY_BYTES (16u*512*4)              //     32,768
#define DEM_BYTES (16u*256*4)              //     16,384

__device__ __forceinline__ u16 f2bf(float f) {
    u32 u = __float_as_uint(f);
    u32 r = (u + 0x7fffu + ((u >> 16) & 1u)) >> 16;
    return (u16)r;
}

__device__ __forceinline__ void gload16(const void* g, void* l) {
    __builtin_amdgcn_global_load_lds(
        (const __attribute__((address_space(1))) u32*)g,
        (__attribute__((address_space(3))) u32*)l, 16, 0, 0);
}

// ---------------- fuseA: style (64 blocks) + wsq (512 blocks) -----------------------
__global__ __launch_bounds__(256)
void fuseA_kernel(const float* __restrict__ s, const float* __restrict__ mod_w,
                  const float* __restrict__ mod_b, const float* __restrict__ weight,
                  float* __restrict__ style, float* __restrict__ wsq) {
    int bid = blockIdx.x, t = threadIdx.x;
    if (bid < 64) {
        int b = bid >> 2, q = bid & 3;
        __shared__ float ss[512];
        for (int i = t; i < 512; i += 256) ss[i] = s[b*512 + i];
        __syncthreads();
        int ci = q*128 + (t >> 1);
        int kh = (t & 1) * 256;
        const float* row = mod_w + (size_t)ci * 512 + kh;
        const float* sh = ss + kh;
        float acc = 0.f;
        for (int k = 0; k < 256; k += 4) {
            float4 m = *reinterpret_cast<const float4*>(row + k);
            acc += m.x*sh[k] + m.y*sh[k+1] + m.z*sh[k+2] + m.w*sh[k+3];
        }
        acc += __shfl_xor(acc, 1);
        if (!(t & 1)) style[b*512 + ci] = acc * 0.04419417382415922f + mod_b[ci];
    } else {
        int idx = (bid - 64) * 256 + t;   // 512*256
        const float* p = weight + (size_t)idx * 9;
        float a = 0.f;
        #pragma unroll
        for (int i = 0; i < 9; ++i) { float v = p[i]; a += v * v; }
        wsq[idx] = a;
    }
}

// ---------------- fuseB: demod (64 blocks) + wbt LDS-transpose (64 blocks) ----------
__global__ __launch_bounds__(256)
void fuseB_kernel(const float* __restrict__ style, const float* __restrict__ wsq,
                  const float* __restrict__ weight, float* __restrict__ demod,
                  u16* __restrict__ wbT) {
    int bid = blockIdx.x, t = threadIdx.x;
    if (bid < 64) {
        int b = bid >> 2, q = bid & 3;
        __shared__ float st2[512];
        for (int i = t; i < 512; i += 256) { float v = style[b*512 + i]; st2[i] = v * v; }
        __syncthreads();
        int co = q*64 + (t >> 2);
        int kq = (t & 3) * 128;
        float acc = 0.f;
        for (int ci = kq; ci < kq + 128; ++ci) acc += st2[ci] * wsq[ci*256 + co];
        acc += __shfl_xor(acc, 1);
        acc += __shfl_xor(acc, 2);
        if (!(t & 3)) demod[b*256 + co] = rsqrtf(acc * (1.0f/4608.0f) + 1e-8f);
    } else {
        // transpose 8 ci-rows: wbT[p][co][ci0+cc] = bf16(weight[ci0+cc][co][p])
        int ci0 = (bid - 64) * 8;
        __shared__ u16 lw[2304][8];
        const float* wbase = weight + (size_t)ci0 * 2304;
        #pragma unroll
        for (int cc = 0; cc < 8; ++cc) {
            #pragma unroll
            for (int k = 0; k < 9; ++k) {
                int f = t + 256*k;
                lw[f][cc] = f2bf(wbase[(size_t)cc*2304 + f]);
            }
        }
        __syncthreads();
        #pragma unroll
        for (int k = 0; k < 9; ++k) {
            int f = t + 256*k;
            int p = f % 9, co = f / 9;
            u16x8 v = *reinterpret_cast<const u16x8*>(&lw[f][0]);
            *reinterpret_cast<u16x8*>(wbT + ((size_t)(p*256 + co))*512 + ci0) = v;
        }
    }
}

// ---------------- norm: xs[b][h][w][ci] = x*rsqrt(mean_ci x^2 + eps)*style/sqrt4608 -
__global__ __launch_bounds__(256)
void norm_kernel(const float* __restrict__ x, const float* __restrict__ style,
                 u16* __restrict__ xs) {
    int h = blockIdx.x, b = blockIdx.y;
    int t = threadIdx.x;
    u16* xrow = xs + ((size_t)b*XP + h)*XP*512;
    if (h == 32) {                       // zero entire pad row (33*512 u16)
        u16x8 z = {0,0,0,0,0,0,0,0};
        for (int i = t; i < 2112; i += 256)
            reinterpret_cast<u16x8*>(xrow)[i] = z;
        return;
    }
    __shared__ float red[8][32];
    __shared__ float sscale[32];
    __shared__ float sstyle[512];
    __shared__ u16 tile[32*512];
    for (int i = t; i < 512; i += 256)
        sstyle[i] = style[b*512 + i] * 0.014731391274719739f;  // 1/sqrt(4608)
    int w = t & 31, cg = t >> 5;
    const float* xb = x + ((size_t)b*512*32 + h)*32;   // + ci*1024 + w

    float vv[64];
    float a = 0.f;
    #pragma unroll
    for (int i = 0; i < 64; ++i) {
        float v = xb[(size_t)(8*i + cg)*1024 + w];
        vv[i] = v;
        a += v * v;
    }
    red[cg][w] = a;
    __syncthreads();
    if (t < 32) {
        float s2 = 0.f;
        #pragma unroll
        for (int g = 0; g < 8; ++g) s2 += red[g][t];
        sscale[t] = rsqrtf(s2 * (1.0f/512.0f) + 1e-8f);
    }
    __syncthreads();
    float sc = sscale[w];
    #pragma unroll
    for (int i = 0; i < 64; ++i) {
        int ci = 8*i + cg;
        float v = vv[i] * sc * sstyle[ci];
        tile[w*512 + ((i ^ (w & 7)) * 8 + cg)] = f2bf(v);
    }
    if (t < 64) {
        u16x8 z = {0,0,0,0,0,0,0,0};
        reinterpret_cast<u16x8*>(xrow + 32*512)[t] = z;
    }
    __syncthreads();
    int wv = t >> 6, gi = t & 63;
    #pragma unroll
    for (int rr = 0; rr < 32; rr += 4) {
        int w2 = rr + wv;
        u16x8 v = *reinterpret_cast<const u16x8*>(&tile[w2*512 + ((gi ^ (w2 & 7)) * 8)]);
        *reinterpret_cast<u16x8*>(&xrow[w2*512 + gi*8]) = v;
    }
}

// ---------------- conv: 128Mx256N, BK=32, 8 waves, 3-buf 1-barrier ------------------
// groups: zz<128 -> cls0 (S=16, dispatched FIRST for tail balance);
//         else g5'=(zz-128)>>7: 0=cls3a(p0,p2->ypad+bias) 1=cls3b(p6,p8->partial)
//         2=cls2 3=cls1 (S=32). 640 blocks total, 2 blocks/CU (144KB LDS).
__global__ __launch_bounds__(512, 4)
void conv_mfma_kernel(const u16* __restrict__ xs, const u16* __restrict__ wbT,
                      const float* __restrict__ demod, const float* __restrict__ bias,
                      u16* __restrict__ ypad, u16* __restrict__ ypadB) {
    // per buf (12288 u16 = 24KB): A[128][32] @0, B[256][32] @4096
    __shared__ __align__(16) u16 sm[3*12288];

    const int zz = blockIdx.x;       // 0..639
    int g5, sub;
    if (zz < 128) { g5 = 4; sub = zz; }
    else          { g5 = (zz - 128) >> 7; sub = (zz - 128) & 127; }
    const int b = sub >> 3, mt = sub & 7;

    int py, px, aof0, aof1, bof0, bof1, S;
    bool toB = false, wbias = true;
    if (g5 == 0)      { py=1; px=1; aof0=RS+512; bof0=0;        aof1=RS; bof1=2*131072; S=32; }
    else if (g5 == 1) { py=1; px=1; aof0=512;    bof0=6*131072; aof1=0;  bof1=8*131072; S=32;
                        toB=true; wbias=false; }
    else if (g5 == 2) { py=1; px=0; aof0=RS;     bof0=1*131072; aof1=0;  bof1=7*131072; S=32; }
    else if (g5 == 3) { py=0; px=1; aof0=512;    bof0=3*131072; aof1=0;  bof1=5*131072; S=32; }
    else              { py=0; px=0; aof0=0;      bof0=4*131072; aof1=0;  bof1=4*131072; S=16; }

    const int t = threadIdx.x;       // 0..511
    const int lane = t & 63, w = t >> 6;
    const int wm0 = (w >> 2) * 64;   // M half: 0/64 (2 M-waves)
    const int wn0 = (w & 3) * 64;    // N quarter: 0/64/128/192 (4 N-waves)
    const int r = lane & 15, q = lane >> 4;
    const int qs = (q ^ ((r >> 1) & 3)) * 8;    // swizzled read granule (u16)
    const int a0 = mt * 4;           // 4 a-rows per block (BM=128)

    const int m0 = t >> 2;                           // staging row 0..127
    const int c8 = (((t & 3) ^ ((t >> 3) & 3))) * 8; // pre-swizzled source granule

    const u16* aB = xs + (size_t)b*XP*RS + ((a0 + (m0 >> 5))*XP + (m0 & 31))*512 + c8;
    const u16* bB = wbT + m0*512 + c8;

    f32x4 acc[4][4];
    #pragma unroll
    for (int i = 0; i < 4; ++i)
        #pragma unroll
        for (int j = 0; j < 4; ++j) { f32x4 z = {0.f,0.f,0.f,0.f}; acc[i][j] = z; }

    auto stage = [&](int s, int buf) {
        int aof = (s >> 4) ? aof1 : aof0;
        int bof = (s >> 4) ? bof1 : bof0;
        int k0 = (s & 15) << 5;
        u16* la = &sm[buf * 12288 + t * 8];
        gload16(aB + aof + k0,             la);            // A rows 0..127
        gload16(bB + bof + k0,             la + 4096);     // B rows 0..127
        gload16(bB + bof + k0 + 128*512,   la + 8192);     // B rows 128..255
    };

    stage(0, 0);
    stage(1, 1);

    int cur = 0;
    for (int s = 0; s < S; ++s) {
        // wait for stage(s); stage(s+1) stays in flight (in-order vmcnt retirement)
        if (s + 1 < S) asm volatile("s_waitcnt vmcnt(3)" ::: "memory");
        else           asm volatile("s_waitcnt vmcnt(0)" ::: "memory");
        __builtin_amdgcn_s_barrier();
        // all waves past barrier => their step s-1 ds_reads of buf (cur+2)%3 have
        // COMPLETED (in-order DS retirement before last dependent MFMA) -> safe.
        if (s + 2 < S) {
            int b2 = cur + 2; if (b2 >= 3) b2 -= 3;
            stage(s + 2, b2);
        }

        const u16* smc = &sm[cur * 12288];
        bf16x8 af[4], bfr[4];
        #pragma unroll
        for (int mi = 0; mi < 4; ++mi)
            af[mi] = *reinterpret_cast<const bf16x8*>(&smc[(wm0 + mi*16 + r)*32 + qs]);
        #pragma unroll
        for (int ni = 0; ni < 4; ++ni)
            bfr[ni] = *reinterpret_cast<const bf16x8*>(&smc[4096 + (wn0 + ni*16 + r)*32 + qs]);

        // compiler-scheduled lgkm interleave (no forced drain)
        __builtin_amdgcn_s_setprio(1);
        #pragma unroll
        for (int mi = 0; mi < 4; ++mi)
            #pragma unroll
            for (int ni = 0; ni < 4; ++ni)
                acc[mi][ni] = __builtin_amdgcn_mfma_f32_16x16x32_bf16(
                    af[mi], bfr[ni], acc[mi][ni], 0, 0, 0);
        __builtin_amdgcn_s_setprio(0);

        cur = (cur == 2) ? 0 : cur + 1;
    }

    // epilogue: val = acc*demod[b,co] (+ bias[co]); cls3b -> compact partial
    float dmv[4], bsv[4];
    #pragma unroll
    for (int ni = 0; ni < 4; ++ni) {
        int co = wn0 + ni*16 + r;
        dmv[ni] = demod[b*256 + co];
        bsv[ni] = wbias ? bias[co] : 0.f;
    }
    #pragma unroll
    for (int mi = 0; mi < 4; ++mi) {
        #pragma unroll
        for (int rg = 0; rg < 4; ++rg) {
            int m = wm0 + mi*16 + q*4 + rg;     // 0..127
            int a = a0 + (m >> 5), bc = m & 31;
            size_t rowbase;
            if (!toB) {
                int oy = 2*a + py + 2, ox = 2*bc + px + 2;
                rowbase = (((size_t)b*YP + oy)*YP + ox)*256;
            } else {
                rowbase = (((size_t)b*32 + a)*32 + bc)*256;
            }
            u16* dst = toB ? ypadB : ypad;
            #pragma unroll
            for (int ni = 0; ni < 4; ++ni) {
                int co = wn0 + ni*16 + r;
                float v = acc[mi][ni][rg] * dmv[ni] + bsv[ni];
                dst[rowbase + co] = f2bf(v);
            }
        }
    }
}

// ---------------- addp: ypad[odd-odd] += ypadB (coalesced RMW) ----------------------
__global__ __launch_bounds__(256)
void addp_kernel(u16* __restrict__ ypad, const u16* __restrict__ ypadB) {
    const int a = blockIdx.x;    // 0..31
    const int b = blockIdx.y;    // 0..15
    const int t = threadIdx.x;
    const u16* src = ypadB + ((size_t)(b*32 + a))*32*256;
    u16* dst = ypad + (((size_t)b*YP + 2*a + 3)*YP + 3)*256;
    #pragma unroll
    for (int i = 0; i < 4; ++i) {
        int f = i*2048 + t*8;
        int bc = f >> 8, co = f & 255;
        u16x8 pv = *reinterpret_cast<const u16x8*>(src + f);
        u16* dp = dst + bc*512 + co;
        u16x8 dv = *reinterpret_cast<const u16x8*>(dp);
        u16x8 ov;
        #pragma unroll
        for (int k = 0; k < 8; ++k) {
            float fv = __uint_as_float(((u32)pv[k]) << 16)
                     + __uint_as_float(((u32)dv[k]) << 16);
            ov[k] = f2bf(fv);
        }
        *reinterpret_cast<u16x8*>(dp) = ov;
    }
}

// ---------------- blur: separable 5x5 binomial + lrelu*sqrt2, 4 rows/block ----------
__global__ __launch_bounds__(256)
void blur_kernel(const u16* __restrict__ ypad, float* __restrict__ out) {
    const int cg  = blockIdx.x;   // 0..3 (64-channel chunk)
    const int oyq = blockIdx.y;   // 0..15 (4 oy rows each)
    const int b   = blockIdx.z;
    const int t = threadIdx.x;
    __shared__ float vlds[4][68][65];   // [oy][cx][ch]

    const int cp  = t & 31;       // channel pair
    const int cxi = t >> 5;       // 0..7
    const int oy0 = oyq * 4;
    const u16* base = ypad + ((size_t)b*YP + oy0)*YP*256 + cg*64 + cp*2;

    #pragma unroll
    for (int j = 0; j < 9; ++j) {
        int cx = j*8 + cxi;
        if (cx < 68) {
            bool cxok = (cx >= 2 && cx <= 65);
            float r0[8], r1[8];
            #pragma unroll
            for (int rr = 0; rr < 8; ++rr) {
                int iy = oy0 + rr;
                bool ok = cxok && (iy >= 2) && (iy <= 65);
                u32 u = ok ? *reinterpret_cast<const u32*>(base + ((size_t)rr*YP + cx)*256) : 0u;
                r0[rr] = __uint_as_float(u << 16);
                r1[rr] = __uint_as_float(u & 0xffff0000u);
            }
            #pragma unroll
            for (int o = 0; o < 4; ++o) {
                float a0 = 0.0625f*(r0[o]+r0[o+4]) + 0.25f*(r0[o+1]+r0[o+3]) + 0.375f*r0[o+2];
                float a1 = 0.0625f*(r1[o]+r1[o+4]) + 0.25f*(r1[o+1]+r1[o+3]) + 0.375f*r1[o+2];
                vlds[o][cx][cp*2]     = a0;
                vlds[o][cx][cp*2 + 1] = a1;
            }
        }
    }
    __syncthreads();

    const int oxl = t & 63;
    const int cq  = t >> 6;       // 0..3
    #pragma unroll
    for (int o = 0; o < 4; ++o) {
        float* ob = out + (((size_t)b*256 + cg*64)*64 + (oy0 + o))*64;
        #pragma unroll
        for (int i = 0; i < 16; ++i) {
            int c = cq*16 + i;
            float v = 0.0625f*(vlds[o][oxl][c] + vlds[o][oxl+4][c])
                    + 0.25f*(vlds[o][oxl+1][c] + vlds[o][oxl+3][c])
                    + 0.375f*vlds[o][oxl+2][c];
            v = (v >= 0.f ? v : 0.2f*v) * 1.4142135623730951f;
            ob[(size_t)c*4096 + oxl] = v;
        }
    }
}

extern "C" void kernel_launch(void* const* d_in, const int* in_sizes, int n_in,
                              void* d_out, int out_size, void* d_ws, size_t ws_size,
                              hipStream_t stream) {
    const float* x      = (const float*)d_in[0];
    const float* s      = (const float*)d_in[1];
    const float* weight = (const float*)d_in[2];
    const float* bias   = (const float*)d_in[3];
    const float* mod_w  = (const float*)d_in[4];
    const float* mod_b  = (const float*)d_in[5];
    float* out = (float*)d_out;

    char* ws = (char*)d_ws;
    size_t off = 0;
    u16*   xs    = (u16*)(ws + off); off += XS_BYTES;
    u16*   ypad  = (u16*)(ws + off); off += YP_BYTES;
    u16*   ypadB = (u16*)(ws + off); off += YB_BYTES;
    u16*   wbT   = (u16*)(ws + off); off += WBT_BYTES;
    float* wsq   = (float*)(ws + off); off += WSQ_BYTES;
    float* style = (float*)(ws + off); off += STY_BYTES;
    float* demod = (float*)(ws + off); off += DEM_BYTES;
    if (ws_size < off) return;  // workspace too small -> visible correctness failure

    fuseA_kernel<<<576, 256, 0, stream>>>(s, mod_w, mod_b, weight, style, wsq);
    fuseB_kernel<<<128, 256, 0, stream>>>(style, wsq, weight, demod, wbT);
    norm_kernel<<<dim3(33, 16), 256, 0, stream>>>(x, style, xs);
    conv_mfma_kernel<<<640, 512, 0, stream>>>(xs, wbT, demod, bias, ypad, ypadB);
    addp_kernel<<<dim3(32, 16), 256, 0, stream>>>(ypad, ypadB);
    blur_kernel<<<dim3(4, 16, 16), 256, 0, stream>>>(ypad, out);
}

// Round 17
// 104.264 us; speedup vs baseline: 3.8792x; 1.0617x over previous
//
#include <hip/hip_runtime.h>

// StyleGAN2 modulated transposed conv block, MI355X bf16-MFMA implementation.
// R17: = R16 with fuseB+norm merged into ONE dispatch (656 blocks): demod (64)
//      + wbt LDS-transpose (64) + norm (528). Saves a launch and overlaps the
//      small GEMV/transpose work with the BW-bound norm. Conv/addp/blur as R16.

typedef unsigned short u16;
typedef unsigned int u32;
typedef __bf16 bf16x8 __attribute__((ext_vector_type(8)));
typedef u16 u16x8 __attribute__((ext_vector_type(8)));
typedef float f32x4 __attribute__((ext_vector_type(4)));

#define CIN 512
#define COUT 256
#define XP 33   // padded xs spatial (32 + 1)
#define YP 68   // padded y spatial (64 + 2*2)
#define RS (XP*512)   // xs row stride in u16 = 16896

#define XS_BYTES  (16u*33*33*512*2)        // 17,842,176
#define YP_BYTES  (16u*68*68*256*2)        // 37,879,808
#define YB_BYTES  (16u*32*32*256*2)        //  8,388,608 (cls3b compact partial)
#define WBT_BYTES (9u*256*512*2)           //  2,359,296
#define WSQ_BYTES (512u*256*4)             //    524,288
#define STY_BYTES (16u*512*4)              //     32,768
#define DEM_BYTES (16u*256*4)              //     16,384

__device__ __forceinline__ u16 f2bf(float f) {
    u32 u = __float_as_uint(f);
    u32 r = (u + 0x7fffu + ((u >> 16) & 1u)) >> 16;
    return (u16)r;
}

__device__ __forceinline__ void gload16(const void* g, void* l) {
    __builtin_amdgcn_global_load_lds(
        (const __attribute__((address_space(1))) u32*)g,
        (__attribute__((address_space(3))) u32*)l, 16, 0, 0);
}

// ---------------- fuseA: style (64 blocks) + wsq (512 blocks) -----------------------
__global__ __launch_bounds__(256)
void fuseA_kernel(const float* __restrict__ s, const float* __restrict__ mod_w,
                  const float* __restrict__ mod_b, const float* __restrict__ weight,
                  float* __restrict__ style, float* __restrict__ wsq) {
    int bid = blockIdx.x, t = threadIdx.x;
    if (bid < 64) {
        int b = bid >> 2, q = bid & 3;
        __shared__ float ss[512];
        for (int i = t; i < 512; i += 256) ss[i] = s[b*512 + i];
        __syncthreads();
        int ci = q*128 + (t >> 1);
        int kh = (t & 1) * 256;
        const float* row = mod_w + (size_t)ci * 512 + kh;
        const float* sh = ss + kh;
        float acc = 0.f;
        for (int k = 0; k < 256; k += 4) {
            float4 m = *reinterpret_cast<const float4*>(row + k);
            acc += m.x*sh[k] + m.y*sh[k+1] + m.z*sh[k+2] + m.w*sh[k+3];
        }
        acc += __shfl_xor(acc, 1);
        if (!(t & 1)) style[b*512 + ci] = acc * 0.04419417382415922f + mod_b[ci];
    } else {
        int idx = (bid - 64) * 256 + t;   // 512*256
        const float* p = weight + (size_t)idx * 9;
        float a = 0.f;
        #pragma unroll
        for (int i = 0; i < 9; ++i) { float v = p[i]; a += v * v; }
        wsq[idx] = a;
    }
}

// ---------------- fuseBN: demod (64) + wbt transpose (64) + norm (528) --------------
__global__ __launch_bounds__(256)
void fuseBN_kernel(const float* __restrict__ style, const float* __restrict__ wsq,
                   const float* __restrict__ weight, const float* __restrict__ x,
                   float* __restrict__ demod, u16* __restrict__ wbT,
                   u16* __restrict__ xs) {
    int bid = blockIdx.x, t = threadIdx.x;
    if (bid < 64) {
        // demod[b,co] = rsqrt(sum_ci style^2*wsq/4608 + 1e-8)
        int b = bid >> 2, q = bid & 3;
        __shared__ float st2[512];
        for (int i = t; i < 512; i += 256) { float v = style[b*512 + i]; st2[i] = v * v; }
        __syncthreads();
        int co = q*64 + (t >> 2);
        int kq = (t & 3) * 128;
        float acc = 0.f;
        for (int ci = kq; ci < kq + 128; ++ci) acc += st2[ci] * wsq[ci*256 + co];
        acc += __shfl_xor(acc, 1);
        acc += __shfl_xor(acc, 2);
        if (!(t & 3)) demod[b*256 + co] = rsqrtf(acc * (1.0f/4608.0f) + 1e-8f);
        return;
    }
    if (bid < 128) {
        // transpose 8 ci-rows: wbT[p][co][ci0+cc] = bf16(weight[ci0+cc][co][p])
        int ci0 = (bid - 64) * 8;
        __shared__ u16 lw[2304][8];
        const float* wbase = weight + (size_t)ci0 * 2304;
        #pragma unroll
        for (int cc = 0; cc < 8; ++cc) {
            #pragma unroll
            for (int k = 0; k < 9; ++k) {
                int f = t + 256*k;
                lw[f][cc] = f2bf(wbase[(size_t)cc*2304 + f]);
            }
        }
        __syncthreads();
        #pragma unroll
        for (int k = 0; k < 9; ++k) {
            int f = t + 256*k;
            int p = f % 9, co = f / 9;
            u16x8 v = *reinterpret_cast<const u16x8*>(&lw[f][0]);
            *reinterpret_cast<u16x8*>(wbT + ((size_t)(p*256 + co))*512 + ci0) = v;
        }
        return;
    }
    // ---- norm: xs[b][h][w][ci] = x*rsqrt(mean_ci x^2+eps)*style[ci]/sqrt(4608)
    int nb = bid - 128;              // 0..527
    int b = nb / 33, h = nb % 33;
    u16* xrow = xs + ((size_t)b*XP + h)*XP*512;
    if (h == 32) {                   // zero entire pad row (33*512 u16)
        u16x8 z = {0,0,0,0,0,0,0,0};
        for (int i = t; i < 2112; i += 256)
            reinterpret_cast<u16x8*>(xrow)[i] = z;
        return;
    }
    __shared__ float red[8][32];
    __shared__ float sscale[32];
    __shared__ float sstyle[512];
    __shared__ u16 tile[32*512];
    for (int i = t; i < 512; i += 256)
        sstyle[i] = style[b*512 + i] * 0.014731391274719739f;  // 1/sqrt(4608)
    int w = t & 31, cg = t >> 5;
    const float* xb = x + ((size_t)b*512*32 + h)*32;   // + ci*1024 + w

    float vv[64];
    float a = 0.f;
    #pragma unroll
    for (int i = 0; i < 64; ++i) {
        float v = xb[(size_t)(8*i + cg)*1024 + w];
        vv[i] = v;
        a += v * v;
    }
    red[cg][w] = a;
    __syncthreads();
    if (t < 32) {
        float s2 = 0.f;
        #pragma unroll
        for (int g = 0; g < 8; ++g) s2 += red[g][t];
        sscale[t] = rsqrtf(s2 * (1.0f/512.0f) + 1e-8f);
    }
    __syncthreads();
    float sc = sscale[w];
    #pragma unroll
    for (int i = 0; i < 64; ++i) {
        int ci = 8*i + cg;
        float v = vv[i] * sc * sstyle[ci];
        tile[w*512 + ((i ^ (w & 7)) * 8 + cg)] = f2bf(v);
    }
    if (t < 64) {
        u16x8 z = {0,0,0,0,0,0,0,0};
        reinterpret_cast<u16x8*>(xrow + 32*512)[t] = z;
    }
    __syncthreads();
    int wv = t >> 6, gi = t & 63;
    #pragma unroll
    for (int rr = 0; rr < 32; rr += 4) {
        int w2 = rr + wv;
        u16x8 v = *reinterpret_cast<const u16x8*>(&tile[w2*512 + ((gi ^ (w2 & 7)) * 8)]);
        *reinterpret_cast<u16x8*>(&xrow[w2*512 + gi*8]) = v;
    }
}

// ---------------- conv: 128Mx256N, BK=32, 8 waves, 3-buf 1-barrier ------------------
// groups: zz<128 -> cls0 (S=16, dispatched FIRST for tail balance);
//         else g5'=(zz-128)>>7: 0=cls3a(p0,p2->ypad+bias) 1=cls3b(p6,p8->partial)
//         2=cls2 3=cls1 (S=32). 640 blocks total, 2 blocks/CU (144KB LDS).
__global__ __launch_bounds__(512, 4)
void conv_mfma_kernel(const u16* __restrict__ xs, const u16* __restrict__ wbT,
                      const float* __restrict__ demod, const float* __restrict__ bias,
                      u16* __restrict__ ypad, u16* __restrict__ ypadB) {
    // per buf (12288 u16 = 24KB): A[128][32] @0, B[256][32] @4096
    __shared__ __align__(16) u16 sm[3*12288];

    const int zz = blockIdx.x;       // 0..639
    int g5, sub;
    if (zz < 128) { g5 = 4; sub = zz; }
    else          { g5 = (zz - 128) >> 7; sub = (zz - 128) & 127; }
    const int b = sub >> 3, mt = sub & 7;

    int py, px, aof0, aof1, bof0, bof1, S;
    bool toB = false, wbias = true;
    if (g5 == 0)      { py=1; px=1; aof0=RS+512; bof0=0;        aof1=RS; bof1=2*131072; S=32; }
    else if (g5 == 1) { py=1; px=1; aof0=512;    bof0=6*131072; aof1=0;  bof1=8*131072; S=32;
                        toB=true; wbias=false; }
    else if (g5 == 2) { py=1; px=0; aof0=RS;     bof0=1*131072; aof1=0;  bof1=7*131072; S=32; }
    else if (g5 == 3) { py=0; px=1; aof0=512;    bof0=3*131072; aof1=0;  bof1=5*131072; S=32; }
    else              { py=0; px=0; aof0=0;      bof0=4*131072; aof1=0;  bof1=4*131072; S=16; }

    const int t = threadIdx.x;       // 0..511
    const int lane = t & 63, w = t >> 6;
    const int wm0 = (w >> 2) * 64;   // M half: 0/64 (2 M-waves)
    const int wn0 = (w & 3) * 64;    // N quarter: 0/64/128/192 (4 N-waves)
    const int r = lane & 15, q = lane >> 4;
    const int qs = (q ^ ((r >> 1) & 3)) * 8;    // swizzled read granule (u16)
    const int a0 = mt * 4;           // 4 a-rows per block (BM=128)

    const int m0 = t >> 2;                           // staging row 0..127
    const int c8 = (((t & 3) ^ ((t >> 3) & 3))) * 8; // pre-swizzled source granule

    const u16* aB = xs + (size_t)b*XP*RS + ((a0 + (m0 >> 5))*XP + (m0 & 31))*512 + c8;
    const u16* bB = wbT + m0*512 + c8;

    f32x4 acc[4][4];
    #pragma unroll
    for (int i = 0; i < 4; ++i)
        #pragma unroll
        for (int j = 0; j < 4; ++j) { f32x4 z = {0.f,0.f,0.f,0.f}; acc[i][j] = z; }

    auto stage = [&](int s, int buf) {
        int aof = (s >> 4) ? aof1 : aof0;
        int bof = (s >> 4) ? bof1 : bof0;
        int k0 = (s & 15) << 5;
        u16* la = &sm[buf * 12288 + t * 8];
        gload16(aB + aof + k0,             la);            // A rows 0..127
        gload16(bB + bof + k0,             la + 4096);     // B rows 0..127
        gload16(bB + bof + k0 + 128*512,   la + 8192);     // B rows 128..255
    };

    stage(0, 0);
    stage(1, 1);

    int cur = 0;
    for (int s = 0; s < S; ++s) {
        // wait for stage(s); stage(s+1) stays in flight (in-order vmcnt retirement)
        if (s + 1 < S) asm volatile("s_waitcnt vmcnt(3)" ::: "memory");
        else           asm volatile("s_waitcnt vmcnt(0)" ::: "memory");
        __builtin_amdgcn_s_barrier();
        // all waves past barrier => their step s-1 ds_reads of buf (cur+2)%3 have
        // COMPLETED (in-order DS retirement before last dependent MFMA) -> safe.
        if (s + 2 < S) {
            int b2 = cur + 2; if (b2 >= 3) b2 -= 3;
            stage(s + 2, b2);
        }

        const u16* smc = &sm[cur * 12288];
        bf16x8 af[4], bfr[4];
        #pragma unroll
        for (int mi = 0; mi < 4; ++mi)
            af[mi] = *reinterpret_cast<const bf16x8*>(&smc[(wm0 + mi*16 + r)*32 + qs]);
        #pragma unroll
        for (int ni = 0; ni < 4; ++ni)
            bfr[ni] = *reinterpret_cast<const bf16x8*>(&smc[4096 + (wn0 + ni*16 + r)*32 + qs]);

        // compiler-scheduled lgkm interleave (no forced drain)
        __builtin_amdgcn_s_setprio(1);
        #pragma unroll
        for (int mi = 0; mi < 4; ++mi)
            #pragma unroll
            for (int ni = 0; ni < 4; ++ni)
                acc[mi][ni] = __builtin_amdgcn_mfma_f32_16x16x32_bf16(
                    af[mi], bfr[ni], acc[mi][ni], 0, 0, 0);
        __builtin_amdgcn_s_setprio(0);

        cur = (cur == 2) ? 0 : cur + 1;
    }

    // epilogue: val = acc*demod[b,co] (+ bias[co]); cls3b -> compact partial
    float dmv[4], bsv[4];
    #pragma unroll
    for (int ni = 0; ni < 4; ++ni) {
        int co = wn0 + ni*16 + r;
        dmv[ni] = demod[b*256 + co];
        bsv[ni] = wbias ? bias[co] : 0.f;
    }
    #pragma unroll
    for (int mi = 0; mi < 4; ++mi) {
        #pragma unroll
        for (int rg = 0; rg < 4; ++rg) {
            int m = wm0 + mi*16 + q*4 + rg;     // 0..127
            int a = a0 + (m >> 5), bc = m & 31;
            size_t rowbase;
            if (!toB) {
                int oy = 2*a + py + 2, ox = 2*bc + px + 2;
                rowbase = (((size_t)b*YP + oy)*YP + ox)*256;
            } else {
                rowbase = (((size_t)b*32 + a)*32 + bc)*256;
            }
            u16* dst = toB ? ypadB : ypad;
            #pragma unroll
            for (int ni = 0; ni < 4; ++ni) {
                int co = wn0 + ni*16 + r;
                float v = acc[mi][ni][rg] * dmv[ni] + bsv[ni];
                dst[rowbase + co] = f2bf(v);
            }
        }
    }
}

// ---------------- addp: ypad[odd-odd] += ypadB (coalesced RMW) ----------------------
__global__ __launch_bounds__(256)
void addp_kernel(u16* __restrict__ ypad, const u16* __restrict__ ypadB) {
    const int a = blockIdx.x;    // 0..31
    const int b = blockIdx.y;    // 0..15
    const int t = threadIdx.x;
    const u16* src = ypadB + ((size_t)(b*32 + a))*32*256;
    u16* dst = ypad + (((size_t)b*YP + 2*a + 3)*YP + 3)*256;
    #pragma unroll
    for (int i = 0; i < 4; ++i) {
        int f = i*2048 + t*8;
        int bc = f >> 8, co = f & 255;
        u16x8 pv = *reinterpret_cast<const u16x8*>(src + f);
        u16* dp = dst + bc*512 + co;
        u16x8 dv = *reinterpret_cast<const u16x8*>(dp);
        u16x8 ov;
        #pragma unroll
        for (int k = 0; k < 8; ++k) {
            float fv = __uint_as_float(((u32)pv[k]) << 16)
                     + __uint_as_float(((u32)dv[k]) << 16);
            ov[k] = f2bf(fv);
        }
        *reinterpret_cast<u16x8*>(dp) = ov;
    }
}

// ---------------- blur: separable 5x5 binomial + lrelu*sqrt2, 4 rows/block ----------
__global__ __launch_bounds__(256)
void blur_kernel(const u16* __restrict__ ypad, float* __restrict__ out) {
    const int cg  = blockIdx.x;   // 0..3 (64-channel chunk)
    const int oyq = blockIdx.y;   // 0..15 (4 oy rows each)
    const int b   = blockIdx.z;
    const int t = threadIdx.x;
    __shared__ float vlds[4][68][65];   // [oy][cx][ch]

    const int cp  = t & 31;       // channel pair
    const int cxi = t >> 5;       // 0..7
    const int oy0 = oyq * 4;
    const u16* base = ypad + ((size_t)b*YP + oy0)*YP*256 + cg*64 + cp*2;

    #pragma unroll
    for (int j = 0; j < 9; ++j) {
        int cx = j*8 + cxi;
        if (cx < 68) {
            bool cxok = (cx >= 2 && cx <= 65);
            float r0[8], r1[8];
            #pragma unroll
            for (int rr = 0; rr < 8; ++rr) {
                int iy = oy0 + rr;
                bool ok = cxok && (iy >= 2) && (iy <= 65);
                u32 u = ok ? *reinterpret_cast<const u32*>(base + ((size_t)rr*YP + cx)*256) : 0u;
                r0[rr] = __uint_as_float(u << 16);
                r1[rr] = __uint_as_float(u & 0xffff0000u);
            }
            #pragma unroll
            for (int o = 0; o < 4; ++o) {
                float a0 = 0.0625f*(r0[o]+r0[o+4]) + 0.25f*(r0[o+1]+r0[o+3]) + 0.375f*r0[o+2];
                float a1 = 0.0625f*(r1[o]+r1[o+4]) + 0.25f*(r1[o+1]+r1[o+3]) + 0.375f*r1[o+2];
                vlds[o][cx][cp*2]     = a0;
                vlds[o][cx][cp*2 + 1] = a1;
            }
        }
    }
    __syncthreads();

    const int oxl = t & 63;
    const int cq  = t >> 6;       // 0..3
    #pragma unroll
    for (int o = 0; o < 4; ++o) {
        float* ob = out + (((size_t)b*256 + cg*64)*64 + (oy0 + o))*64;
        #pragma unroll
        for (int i = 0; i < 16; ++i) {
            int c = cq*16 + i;
            float v = 0.0625f*(vlds[o][oxl][c] + vlds[o][oxl+4][c])
                    + 0.25f*(vlds[o][oxl+1][c] + vlds[o][oxl+3][c])
                    + 0.375f*vlds[o][oxl+2][c];
            v = (v >= 0.f ? v : 0.2f*v) * 1.4142135623730951f;
            ob[(size_t)c*4096 + oxl] = v;
        }
    }
}

extern "C" void kernel_launch(void* const* d_in, const int* in_sizes, int n_in,
                              void* d_out, int out_size, void* d_ws, size_t ws_size,
                              hipStream_t stream) {
    const float* x      = (const float*)d_in[0];
    const float* s      = (const float*)d_in[1];
    const float* weight = (const float*)d_in[2];
    const float* bias   = (const float*)d_in[3];
    const float* mod_w  = (const float*)d_in[4];
    const float* mod_b  = (const float*)d_in[5];
    float* out = (float*)d_out;

    char* ws = (char*)d_ws;
    size_t off = 0;
    u16*   xs    = (u16*)(ws + off); off += XS_BYTES;
    u16*   ypad  = (u16*)(ws + off); off += YP_BYTES;
    u16*   ypadB = (u16*)(ws + off); off += YB_BYTES;
    u16*   wbT   = (u16*)(ws + off); off += WBT_BYTES;
    float* wsq   = (float*)(ws + off); off += WSQ_BYTES;
    float* style = (float*)(ws + off); off += STY_BYTES;
    float* demod = (float*)(ws + off); off += DEM_BYTES;
    if (ws_size < off) return;  // workspace too small -> visible correctness failure

    fuseA_kernel<<<576, 256, 0, stream>>>(s, mod_w, mod_b, weight, style, wsq);
    fuseBN_kernel<<<656, 256, 0, stream>>>(style, wsq, weight, x, demod, wbT, xs);
    conv_mfma_kernel<<<640, 512, 0, stream>>>(xs, wbT, demod, bias, ypad, ypadB);
    addp_kernel<<<dim3(32, 16), 256, 0, stream>>>(ypad, ypadB);
    blur_kernel<<<dim3(4, 16, 16), 256, 0, stream>>>(ypad, out);
}